// Round 10
// baseline (486.115 us; speedup 1.0000x reference)
//
#include <hip/hip_runtime.h>
#include <hip/hip_bf16.h>

typedef unsigned short u16;
typedef unsigned int u32;
typedef unsigned long long u64;
typedef __bf16 bf16x8 __attribute__((ext_vector_type(8)));
typedef float f32x16 __attribute__((ext_vector_type(16)));
typedef float f32x4 __attribute__((ext_vector_type(4)));

#define TEMP_INV (1.0f / 0.07f)
#define LOG2E 1.4426950408889634f

#if __has_builtin(__builtin_amdgcn_exp2f)
#define EXP2(x) __builtin_amdgcn_exp2f(x)
#else
#define EXP2(x) exp2f(x)
#endif

// B-resident fragment gather from f32 row-major [.,128], cvt to bf16 in-register.
__device__ __forceinline__ bf16x8 ldfrag(const float* __restrict__ base, int row, int koff) {
    const float* p = base + (size_t)row * 128 + koff;
    f32x4 a = *(const f32x4*)p;
    f32x4 b = *(const f32x4*)(p + 4);
    bf16x8 r;
    r[0] = (__bf16)a[0]; r[1] = (__bf16)a[1]; r[2] = (__bf16)a[2]; r[3] = (__bf16)a[3];
    r[4] = (__bf16)b[0]; r[5] = (__bf16)b[1]; r[6] = (__bf16)b[2]; r[7] = (__bf16)b[3];
    return r;
}

// LDS tile: 32 rows x 136-u16 stride (272 B odd 16B multiple -> b128 conflict-free, r6/r8-verified)
#define TSTRIDE 136
#define TMAT 4352
#define BUFU (2 * TMAT)

__device__ __forceinline__ void ld_tile(f32x4 pa[2][2][2],
        const float* __restrict__ m0, const float* __restrict__ m1,
        int j0, int r0, int c16) {
    const float* p00 = m0 + (size_t)(j0 + r0) * 128 + c16 * 8;
    const float* p01 = m0 + (size_t)(j0 + r0 + 16) * 128 + c16 * 8;
    const float* p10 = m1 + (size_t)(j0 + r0) * 128 + c16 * 8;
    const float* p11 = m1 + (size_t)(j0 + r0 + 16) * 128 + c16 * 8;
    pa[0][0][0] = *(const f32x4*)p00; pa[0][0][1] = *(const f32x4*)(p00 + 4);
    pa[0][1][0] = *(const f32x4*)p01; pa[0][1][1] = *(const f32x4*)(p01 + 4);
    pa[1][0][0] = *(const f32x4*)p10; pa[1][0][1] = *(const f32x4*)(p10 + 4);
    pa[1][1][0] = *(const f32x4*)p11; pa[1][1][1] = *(const f32x4*)(p11 + 4);
}

__device__ __forceinline__ void st_tile(u16* __restrict__ buf, f32x4 pa[2][2][2],
                                        int r0, int c16) {
#pragma unroll
    for (int m = 0; m < 2; ++m)
#pragma unroll
        for (int rh = 0; rh < 2; ++rh) {
            f32x4 a = pa[m][rh][0], b = pa[m][rh][1];
            bf16x8 cv;
            cv[0] = (__bf16)a[0]; cv[1] = (__bf16)a[1]; cv[2] = (__bf16)a[2]; cv[3] = (__bf16)a[3];
            cv[4] = (__bf16)b[0]; cv[5] = (__bf16)b[1]; cv[6] = (__bf16)b[2]; cv[7] = (__bf16)b[3];
            *(bf16x8*)(buf + m * TMAT + (size_t)(r0 + rh * 16) * TSTRIDE + c16 * 8) = cv;
        }
}

// ctrl layout (u32): [0]=pool_work, [1]=pool_done, [2..17]=group tickets, [18]=ticket2, [19]=accum(f32)
// ---------------- Single fused kernel ----------------
// grid (32,32): bi=i-chunk (128 rows), bj=j-chunk (128 cols).
// Phase A: first 32 arriving blocks each compute pool max for one 128-i slice (work stealing,
//          deadlock-free: workers never wait on non-arrived blocks).
// Gate:    all blocks wait for pool_done==32 (fenced, r9-proven pattern).
// Phase C: r8's two-pass main loop verbatim (dbuf LDS, 1 barrier/tile, no launch_bounds).
// Tail:    per-group ticket (64 blocks/group); last arrival reduces its m; global ticket writes out.
__global__ void k_fused(
    const float* __restrict__ zp, const float* __restrict__ sp,
    const float* __restrict__ fp, const float* __restrict__ xp,
    const float* __restrict__ pag, const float* __restrict__ psp,
    const float* __restrict__ mnb,
    float* __restrict__ P /* [32][6][4096] */,
    float* __restrict__ Rf, float* __restrict__ Rs,
    u32* __restrict__ ctrl, u32* __restrict__ out) {
    __shared__ u16 stile[2 * BUFU];   // 34816 B
    __shared__ float sT[512];         // RfI[128] RsI[128] RfJ[128] RsJ[128]
    __shared__ u32 sFlag;

    int tid = threadIdx.x;
    int lane = tid & 63, w = tid >> 6;
    int half = lane >> 5, li = lane & 31;
    int bi = blockIdx.x, bj = blockIdx.y;
    int i = bi * 128 + w * 32 + li;
    int cbase = bj * 128;
    int r0 = tid >> 4, c16 = tid & 15;
    const float c1 = TEMP_INV * LOG2E;

    // ---- phase A: pool max work stealing ----
    if (tid == 0) sFlag = atomicAdd(&ctrl[0], 1u);
    __syncthreads();
    u32 slice = sFlag;
    if (slice < 32) {
        int ip = (int)slice * 128 + w * 32 + li;
        bf16x8 prf[8], prs[8];
#pragma unroll
        for (int kc = 0; kc < 8; ++kc) {
            int koff = kc * 16 + half * 8;
            prf[kc] = ldfrag(fp, ip, koff);
            prs[kc] = ldfrag(sp, ip, koff);
        }
        f32x4 pa2[2][2][2];
        ld_tile(pa2, pag, psp, 0, r0, c16);
        float rmf = -1e30f, rms = -1e30f;
        for (int pt = 0; pt < 32; ++pt) {
            __syncthreads();
            st_tile(stile, pa2, r0, c16);
            __syncthreads();
            if (pt < 31) ld_tile(pa2, pag, psp, (pt + 1) * 32, r0, c16);
            f32x16 accf = {}; f32x16 accs = {};
#pragma unroll
            for (int kc = 0; kc < 8; ++kc) {
                const u16* ab = stile + li * TSTRIDE + kc * 16 + half * 8;
                bf16x8 a0 = *(const bf16x8*)ab;
                bf16x8 a1 = *(const bf16x8*)(ab + TMAT);
                accf = __builtin_amdgcn_mfma_f32_32x32x16_bf16(a0, prf[kc], accf, 0, 0, 0);
                accs = __builtin_amdgcn_mfma_f32_32x32x16_bf16(a1, prs[kc], accs, 0, 0, 0);
            }
#pragma unroll
            for (int r = 0; r < 16; ++r) {
                rmf = fmaxf(rmf, accf[r]);
                rms = fmaxf(rms, accs[r]);
            }
        }
        rmf = fmaxf(rmf, __shfl_xor(rmf, 32, 64));
        rms = fmaxf(rms, __shfl_xor(rms, 32, 64));
        if (half == 0) { Rf[ip] = rmf; Rs[ip] = rms; }
        __threadfence();
        __syncthreads();
        if (tid == 0) atomicAdd(&ctrl[1], 1u);
    }

    // resident fragments for pass 0: f, s_pr
    bf16x8 bres0[8], bres1[8];
#pragma unroll
    for (int kc = 0; kc < 8; ++kc) {
        int koff = kc * 16 + half * 8;
        bres0[kc] = ldfrag(fp, i, koff);
        bres1[kc] = ldfrag(sp, i, koff);
    }
    // prefetch main tile 0 (hides under the gate spin)
    f32x4 pa[2][2][2];
    ld_tile(pa, fp, sp, cbase, r0, c16);

    // ---- gate: wait for all 32 pool slices (arrival-based, deadlock-free) ----
    if (tid == 0) {
        while (__hip_atomic_load(&ctrl[1], __ATOMIC_RELAXED, __HIP_MEMORY_SCOPE_AGENT) < 32u)
            __builtin_amdgcn_s_sleep(4);
    }
    __syncthreads();
    __threadfence();   // acquire: Rf/Rs visible

    // ---- Rf/Rs LDS tables for my i-rows and j-cols ----
    {
        int row = (tid < 128) ? (bi * 128 + tid) : (cbase + tid - 128);
        float mf = Rf[row], ms = Rs[row];
        if (tid < 128) { sT[tid] = mf; sT[128 + tid] = ms; }
        else           { sT[256 + (tid - 128)] = mf; sT[384 + (tid - 128)] = ms; }
    }
    __syncthreads();               // pool-phase stile reads fully done (also covers table)
    st_tile(stile, pa, r0, c16);   // buffer 0 <- main tile 0
    __syncthreads();

    float rfi = sT[w * 32 + li], rsi = sT[128 + w * 32 + li];
    const float* sRfJ = sT + 256;
    const float* sRsJ = sT + 384;
    const float* mrow = mnb + (size_t)(i & 255) * 4096 + cbase;
    float wsum = 0.f, ones = 0.f, Az = 0.f, Ax = 0.f, Zz = 0.f, Zx = 0.f;
    u64 bitsv[4];

    // ---- phase C: main two-pass loop (r8 structure: dbuf, 1 barrier/tile) ----
#pragma unroll
    for (int jt = 0; jt < 8; ++jt) {
        int j0l = (jt & 3) * 32;
        u16* bufC = stile + (jt & 1) * BUFU;
        u16* bufW = stile + ((jt + 1) & 1) * BUFU;

        if (jt < 7) {
            const float* n0 = (jt + 1 < 4) ? fp : zp;
            const float* n1 = (jt + 1 < 4) ? sp : xp;
            ld_tile(pa, n0, n1, cbase + ((jt + 1) & 3) * 32, r0, c16);
        }

        if (jt < 4) {
            f32x16 accF = {}; f32x16 accS = {};
#pragma unroll
            for (int kc = 0; kc < 8; ++kc) {
                const u16* ab = bufC + li * TSTRIDE + kc * 16 + half * 8;
                bf16x8 a0 = *(const bf16x8*)ab;
                bf16x8 a1 = *(const bf16x8*)(ab + TMAT);
                accF = __builtin_amdgcn_mfma_f32_32x32x16_bf16(a0, bres0[kc], accF, 0, 0, 0);
                accS = __builtin_amdgcn_mfma_f32_32x32x16_bf16(a1, bres1[kc], accS, 0, 0, 0);
            }
            // elem r: local j = j0l + (r&3) + 8*(r>>2) + 4*half  (m74/m101 C/D layout)
            u64 bits = 0;
#pragma unroll
            for (int qq = 0; qq < 4; ++qq) {
                int jbl = j0l + qq * 8 + half * 4;
                f32x4 rfj4 = *(const f32x4*)(sRfJ + jbl);
                f32x4 rsj4 = *(const f32x4*)(sRsJ + jbl);
                f32x4 mb4 = *(const f32x4*)(mrow + jbl);
#pragma unroll
                for (int t = 0; t < 4; ++t) {
                    int r = qq * 4 + t;
                    int j = cbase + jbl + t;
                    bool nm = (j != i);
                    bool mob = accF[r] > fminf(rfi, rfj4[t]);
                    bool meb = accS[r] > fminf(rsi, rsj4[t]);
                    bool mnbv = mb4[t] > 0.0f;
                    u32 e = ((mob && nm) ? 1u : 0u) | ((meb && nm) ? 2u : 0u) |
                            (((mob || mnbv) && nm) ? 4u : 0u);
                    bits |= (u64)e << (4 * r);
                }
            }
            bitsv[jt] = bits;
            if (jt == 3) {
#pragma unroll
                for (int kc = 0; kc < 8; ++kc) {
                    int koff = kc * 16 + half * 8;
                    bres0[kc] = ldfrag(zp, i, koff);
                    bres1[kc] = ldfrag(xp, i, koff);
                }
            }
        } else {
            f32x16 accZ = {}; f32x16 accX = {};
#pragma unroll
            for (int kc = 0; kc < 8; ++kc) {
                const u16* ab = bufC + li * TSTRIDE + kc * 16 + half * 8;
                bf16x8 a0 = *(const bf16x8*)ab;
                bf16x8 a1 = *(const bf16x8*)(ab + TMAT);
                accZ = __builtin_amdgcn_mfma_f32_32x32x16_bf16(a0, bres0[kc], accZ, 0, 0, 0);
                accX = __builtin_amdgcn_mfma_f32_32x32x16_bf16(a1, bres1[kc], accX, 0, 0, 0);
            }
            u64 bits = bitsv[jt & 3];
#pragma unroll
            for (int r = 0; r < 16; ++r) {
                u32 e = (u32)(bits >> (4 * r)) & 7u;
                float w1 = (e & 1u) ? 1.0f : 0.0f;
                float wv = w1 + ((e & 2u) ? 0.5f : 0.0f);
                float ng = (e & 4u) ? 1.0f : 0.0f;
                float lvz = accZ[r], lvx = accX[r];
                wsum += wv; ones += w1;
                Az = fmaf(wv, lvz, Az);
                Ax = fmaf(wv, lvx, Ax);
                Zz = fmaf(ng, EXP2(fmaf(lvz, c1, -c1)), Zz);
                Zx = fmaf(ng, EXP2(fmaf(lvx, c1, -c1)), Zx);
            }
        }

        if (jt < 7) st_tile(bufW, pa, r0, c16);
        __syncthreads();
    }

    // combine lane-halves; coalesced SoA partial store
    wsum += __shfl_xor(wsum, 32, 64);
    ones += __shfl_xor(ones, 32, 64);
    Az += __shfl_xor(Az, 32, 64);
    Ax += __shfl_xor(Ax, 32, 64);
    Zz += __shfl_xor(Zz, 32, 64);
    Zx += __shfl_xor(Zx, 32, 64);
    if (half == 0) {
        float* pb = P + ((size_t)bj * 6) * 4096 + i;
        pb[0] = wsum;
        pb[4096] = ones;
        pb[2 * 4096] = Az;
        pb[3 * 4096] = Ax;
        pb[4 * 4096] = Zz;
        pb[5 * 4096] = Zx;
    }

    // ---- tail: per-group ticket; last arrival of group g reduces m=g ----
    __threadfence();
    __syncthreads();
    int g = bi >> 1;   // 16 groups x 64 blocks (2 bi x 32 bj)
    if (tid == 0) sFlag = atomicAdd(&ctrl[2 + g], 1u);
    __syncthreads();
    if (sFlag == 63u) {
        __threadfence();   // acquire group's P partials
        int row = g * 256 + tid;
        float tw = 0.f, to = 0.f, tAz = 0.f, tAx = 0.f, tZz = 0.f, tZx = 0.f;
#pragma unroll
        for (int c = 0; c < 32; ++c) {
            const float* pb = P + ((size_t)c * 6) * 4096 + row;
            tw += pb[0];
            to += pb[4096];
            tAz += pb[2 * 4096];
            tAx += pb[3 * 4096];
            tZz += pb[4 * 4096];
            tZx += pb[5 * 4096];
        }
        float dw = tw > 0.f ? tw : 1.0f;
        float lz = tZz > 0.f ? logf(tZz) : 0.f;
        float lx = tZx > 0.f ? logf(tZx) : 0.f;
        float mlz = (TEMP_INV * tAz - tw * (TEMP_INV + lz)) / dw;
        float mlx = (TEMP_INV * tAx - tw * (TEMP_INV + lx)) / dw;
        float si = to > 0.f ? tw : 0.f;
        float ci = (mlz + mlx) * si;
#pragma unroll
        for (int d = 1; d < 64; d <<= 1) {
            ci += __shfl_xor(ci, d, 64);
            si += __shfl_xor(si, d, 64);
        }
        if ((tid & 63) == 0) { sT[tid >> 6] = ci; sT[8 + (tid >> 6)] = si; }
        __syncthreads();
        if (tid == 0) {
            float cs = sT[0] + sT[1] + sT[2] + sT[3];
            float ss = sT[8] + sT[9] + sT[10] + sT[11];
            float ratio = ss > 0.f ? cs / ss : 0.f;
            float* accum = (float*)&ctrl[19];
            atomicAdd(accum, ratio);
            __threadfence();
            u32 old2 = atomicAdd(&ctrl[18], 1u);
            if (old2 == 15u) {
                float total = atomicAdd(accum, 0.0f);  // all 16 group adds complete
                __hip_bfloat16 hb = __float2bfloat16(-total / 32.0f);
                u32 bits = (u32)__bfloat16_as_ushort(hb);
                out[0] = (bits << 16) | bits;  // bf16/f32 dual-interpretation hedge (passed r3-r9)
            }
        }
    }
}

extern "C" void kernel_launch(void* const* d_in, const int* in_sizes, int n_in,
                              void* d_out, int out_size, void* d_ws, size_t ws_size,
                              hipStream_t stream) {
    const float* z   = (const float*)d_in[0];
    const float* spr = (const float*)d_in[1];
    const float* f   = (const float*)d_in[2];
    const float* pag = (const float*)d_in[3];
    const float* psp = (const float*)d_in[4];
    const float* zmx = (const float*)d_in[5];
    const float* mnb = (const float*)d_in[6];

    // ws: P[32][6][4096] f32 (3 MB) | Rf[4096] | Rs[4096] | ctrl[32]
    float* P  = (float*)d_ws;
    float* Rf = P + (size_t)32 * 6 * 4096;
    float* Rs = Rf + 4096;
    u32* ctrl = (u32*)(Rs + 4096);

    hipMemsetAsync(ctrl, 0, 128, stream);
    k_fused<<<dim3(32, 32), 256, 0, stream>>>(z, spr, f, zmx, pag, psp, mnb,
                                              P, Rf, Rs, ctrl, (u32*)d_out);
}

// Round 11
// 346.171 us; speedup vs baseline: 1.4043x; 1.4043x over previous
//
#include <hip/hip_runtime.h>
#include <hip/hip_bf16.h>

typedef unsigned short u16;
typedef unsigned int u32;
typedef unsigned long long u64;
typedef __bf16 bf16x8 __attribute__((ext_vector_type(8)));
typedef float f32x16 __attribute__((ext_vector_type(16)));
typedef float f32x4 __attribute__((ext_vector_type(4)));

#define TEMP_INV (1.0f / 0.07f)
#define LOG2E 1.4426950408889634f

#if __has_builtin(__builtin_amdgcn_exp2f)
#define EXP2(x) __builtin_amdgcn_exp2f(x)
#else
#define EXP2(x) exp2f(x)
#endif

// B-resident fragment gather from f32 row-major [.,128], cvt to bf16 in-register.
__device__ __forceinline__ bf16x8 ldfrag(const float* __restrict__ base, int row, int koff) {
    const float* p = base + (size_t)row * 128 + koff;
    f32x4 a = *(const f32x4*)p;
    f32x4 b = *(const f32x4*)(p + 4);
    bf16x8 r;
    r[0] = (__bf16)a[0]; r[1] = (__bf16)a[1]; r[2] = (__bf16)a[2]; r[3] = (__bf16)a[3];
    r[4] = (__bf16)b[0]; r[5] = (__bf16)b[1]; r[6] = (__bf16)b[2]; r[7] = (__bf16)b[3];
    return r;
}

// LDS tile: 32 rows x 136-u16 stride (272 B odd 16B multiple -> b128 conflict-free, r6/r8-verified)
#define TSTRIDE 136
#define TMAT 4352
#define BUFU (2 * TMAT)

__device__ __forceinline__ void ld_tile(f32x4 pa[2][2][2],
        const float* __restrict__ m0, const float* __restrict__ m1,
        int j0, int r0, int c16) {
    const float* p00 = m0 + (size_t)(j0 + r0) * 128 + c16 * 8;
    const float* p01 = m0 + (size_t)(j0 + r0 + 16) * 128 + c16 * 8;
    const float* p10 = m1 + (size_t)(j0 + r0) * 128 + c16 * 8;
    const float* p11 = m1 + (size_t)(j0 + r0 + 16) * 128 + c16 * 8;
    pa[0][0][0] = *(const f32x4*)p00; pa[0][0][1] = *(const f32x4*)(p00 + 4);
    pa[0][1][0] = *(const f32x4*)p01; pa[0][1][1] = *(const f32x4*)(p01 + 4);
    pa[1][0][0] = *(const f32x4*)p10; pa[1][0][1] = *(const f32x4*)(p10 + 4);
    pa[1][1][0] = *(const f32x4*)p11; pa[1][1][1] = *(const f32x4*)(p11 + 4);
}

__device__ __forceinline__ void st_tile(u16* __restrict__ buf, f32x4 pa[2][2][2],
                                        int r0, int c16) {
#pragma unroll
    for (int m = 0; m < 2; ++m)
#pragma unroll
        for (int rh = 0; rh < 2; ++rh) {
            f32x4 a = pa[m][rh][0], b = pa[m][rh][1];
            bf16x8 cv;
            cv[0] = (__bf16)a[0]; cv[1] = (__bf16)a[1]; cv[2] = (__bf16)a[2]; cv[3] = (__bf16)a[3];
            cv[4] = (__bf16)b[0]; cv[5] = (__bf16)b[1]; cv[6] = (__bf16)b[2]; cv[7] = (__bf16)b[3];
            *(bf16x8*)(buf + m * TMAT + (size_t)(r0 + rh * 16) * TSTRIDE + c16 * 8) = cv;
        }
}

// ctrl layout (u32): [0]=pool_work, [1]=pool_done, [2..17]=group tickets, [18]=ticket2, [19]=accum(f32)
// ---------------- Single fused kernel ----------------
// __launch_bounds__(256) ONLY (no min-waves): r6/r8-proven — tells the compiler the true block
// size without an occupancy-driven VGPR cap. (r7=(256,3)->84, r9=(256,4)->64, r10=none->64: all spilled.)
__global__ __launch_bounds__(256) void k_fused(
    const float* __restrict__ zp, const float* __restrict__ sp,
    const float* __restrict__ fp, const float* __restrict__ xp,
    const float* __restrict__ pag, const float* __restrict__ psp,
    const float* __restrict__ mnb,
    float* __restrict__ P /* [32][6][4096] */,
    float* __restrict__ Rf, float* __restrict__ Rs,
    u32* __restrict__ ctrl, u32* __restrict__ out) {
    __shared__ u16 stile[2 * BUFU];   // 34816 B
    __shared__ float sT[512];         // RfI[128] RsI[128] RfJ[128] RsJ[128]
    __shared__ u32 sFlag;

    int tid = threadIdx.x;
    int lane = tid & 63, w = tid >> 6;
    int half = lane >> 5, li = lane & 31;
    int bi = blockIdx.x, bj = blockIdx.y;
    int i = bi * 128 + w * 32 + li;
    int cbase = bj * 128;
    int r0 = tid >> 4, c16 = tid & 15;
    const float c1 = TEMP_INV * LOG2E;

    // ---- phase A: pool max work stealing (first 32 arriving blocks) ----
    if (tid == 0) sFlag = atomicAdd(&ctrl[0], 1u);
    __syncthreads();
    u32 slice = sFlag;
    if (slice < 32) {
        int ip = (int)slice * 128 + w * 32 + li;
        bf16x8 prf[8], prs[8];
#pragma unroll
        for (int kc = 0; kc < 8; ++kc) {
            int koff = kc * 16 + half * 8;
            prf[kc] = ldfrag(fp, ip, koff);
            prs[kc] = ldfrag(sp, ip, koff);
        }
        f32x4 pa2[2][2][2];
        ld_tile(pa2, pag, psp, 0, r0, c16);
        float rmf = -1e30f, rms = -1e30f;
        for (int pt = 0; pt < 32; ++pt) {
            __syncthreads();
            st_tile(stile, pa2, r0, c16);
            __syncthreads();
            if (pt < 31) ld_tile(pa2, pag, psp, (pt + 1) * 32, r0, c16);
            f32x16 accf = {}; f32x16 accs = {};
#pragma unroll
            for (int kc = 0; kc < 8; ++kc) {
                const u16* ab = stile + li * TSTRIDE + kc * 16 + half * 8;
                bf16x8 a0 = *(const bf16x8*)ab;
                bf16x8 a1 = *(const bf16x8*)(ab + TMAT);
                accf = __builtin_amdgcn_mfma_f32_32x32x16_bf16(a0, prf[kc], accf, 0, 0, 0);
                accs = __builtin_amdgcn_mfma_f32_32x32x16_bf16(a1, prs[kc], accs, 0, 0, 0);
            }
#pragma unroll
            for (int r = 0; r < 16; ++r) {
                rmf = fmaxf(rmf, accf[r]);
                rms = fmaxf(rms, accs[r]);
            }
        }
        rmf = fmaxf(rmf, __shfl_xor(rmf, 32, 64));
        rms = fmaxf(rms, __shfl_xor(rms, 32, 64));
        if (half == 0) { Rf[ip] = rmf; Rs[ip] = rms; }
        __threadfence();
        __syncthreads();
        if (tid == 0) atomicAdd(&ctrl[1], 1u);
    }

    // resident fragments for pass 0: f, s_pr
    bf16x8 bres0[8], bres1[8];
#pragma unroll
    for (int kc = 0; kc < 8; ++kc) {
        int koff = kc * 16 + half * 8;
        bres0[kc] = ldfrag(fp, i, koff);
        bres1[kc] = ldfrag(sp, i, koff);
    }
    // prefetch main tile 0 (hides under the gate spin)
    f32x4 pa[2][2][2];
    ld_tile(pa, fp, sp, cbase, r0, c16);

    // ---- gate: wait for all 32 pool slices (arrival-based, deadlock-free) ----
    if (tid == 0) {
        while (__hip_atomic_load(&ctrl[1], __ATOMIC_RELAXED, __HIP_MEMORY_SCOPE_AGENT) < 32u)
            __builtin_amdgcn_s_sleep(4);
    }
    __syncthreads();
    __threadfence();   // acquire: Rf/Rs visible

    // ---- Rf/Rs LDS tables for my i-rows and j-cols ----
    {
        int row = (tid < 128) ? (bi * 128 + tid) : (cbase + tid - 128);
        float mf = Rf[row], ms = Rs[row];
        if (tid < 128) { sT[tid] = mf; sT[128 + tid] = ms; }
        else           { sT[256 + (tid - 128)] = mf; sT[384 + (tid - 128)] = ms; }
    }
    __syncthreads();               // pool-phase stile reads fully done (also covers table)
    st_tile(stile, pa, r0, c16);   // buffer 0 <- main tile 0
    __syncthreads();

    float rfi = sT[w * 32 + li], rsi = sT[128 + w * 32 + li];
    const float* sRfJ = sT + 256;
    const float* sRsJ = sT + 384;
    const float* mrow = mnb + (size_t)(i & 255) * 4096 + cbase;
    float wsum = 0.f, ones = 0.f, Az = 0.f, Ax = 0.f, Zz = 0.f, Zx = 0.f;
    u64 bitsv[4];

    // ---- phase C: main two-pass loop (r8 structure: dbuf, 1 barrier/tile) ----
#pragma unroll
    for (int jt = 0; jt < 8; ++jt) {
        int j0l = (jt & 3) * 32;
        u16* bufC = stile + (jt & 1) * BUFU;
        u16* bufW = stile + ((jt + 1) & 1) * BUFU;

        if (jt < 7) {
            const float* n0 = (jt + 1 < 4) ? fp : zp;
            const float* n1 = (jt + 1 < 4) ? sp : xp;
            ld_tile(pa, n0, n1, cbase + ((jt + 1) & 3) * 32, r0, c16);
        }

        if (jt < 4) {
            f32x16 accF = {}; f32x16 accS = {};
#pragma unroll
            for (int kc = 0; kc < 8; ++kc) {
                const u16* ab = bufC + li * TSTRIDE + kc * 16 + half * 8;
                bf16x8 a0 = *(const bf16x8*)ab;
                bf16x8 a1 = *(const bf16x8*)(ab + TMAT);
                accF = __builtin_amdgcn_mfma_f32_32x32x16_bf16(a0, bres0[kc], accF, 0, 0, 0);
                accS = __builtin_amdgcn_mfma_f32_32x32x16_bf16(a1, bres1[kc], accS, 0, 0, 0);
            }
            // elem r: local j = j0l + (r&3) + 8*(r>>2) + 4*half  (m74/m101 C/D layout)
            u64 bits = 0;
#pragma unroll
            for (int qq = 0; qq < 4; ++qq) {
                int jbl = j0l + qq * 8 + half * 4;
                f32x4 rfj4 = *(const f32x4*)(sRfJ + jbl);
                f32x4 rsj4 = *(const f32x4*)(sRsJ + jbl);
                f32x4 mb4 = *(const f32x4*)(mrow + jbl);
#pragma unroll
                for (int t = 0; t < 4; ++t) {
                    int r = qq * 4 + t;
                    int j = cbase + jbl + t;
                    bool nm = (j != i);
                    bool mob = accF[r] > fminf(rfi, rfj4[t]);
                    bool meb = accS[r] > fminf(rsi, rsj4[t]);
                    bool mnbv = mb4[t] > 0.0f;
                    u32 e = ((mob && nm) ? 1u : 0u) | ((meb && nm) ? 2u : 0u) |
                            (((mob || mnbv) && nm) ? 4u : 0u);
                    bits |= (u64)e << (4 * r);
                }
            }
            bitsv[jt] = bits;
            if (jt == 3) {
#pragma unroll
                for (int kc = 0; kc < 8; ++kc) {
                    int koff = kc * 16 + half * 8;
                    bres0[kc] = ldfrag(zp, i, koff);
                    bres1[kc] = ldfrag(xp, i, koff);
                }
            }
        } else {
            f32x16 accZ = {}; f32x16 accX = {};
#pragma unroll
            for (int kc = 0; kc < 8; ++kc) {
                const u16* ab = bufC + li * TSTRIDE + kc * 16 + half * 8;
                bf16x8 a0 = *(const bf16x8*)ab;
                bf16x8 a1 = *(const bf16x8*)(ab + TMAT);
                accZ = __builtin_amdgcn_mfma_f32_32x32x16_bf16(a0, bres0[kc], accZ, 0, 0, 0);
                accX = __builtin_amdgcn_mfma_f32_32x32x16_bf16(a1, bres1[kc], accX, 0, 0, 0);
            }
            u64 bits = bitsv[jt & 3];
#pragma unroll
            for (int r = 0; r < 16; ++r) {
                u32 e = (u32)(bits >> (4 * r)) & 7u;
                float w1 = (e & 1u) ? 1.0f : 0.0f;
                float wv = w1 + ((e & 2u) ? 0.5f : 0.0f);
                float ng = (e & 4u) ? 1.0f : 0.0f;
                float lvz = accZ[r], lvx = accX[r];
                wsum += wv; ones += w1;
                Az = fmaf(wv, lvz, Az);
                Ax = fmaf(wv, lvx, Ax);
                Zz = fmaf(ng, EXP2(fmaf(lvz, c1, -c1)), Zz);
                Zx = fmaf(ng, EXP2(fmaf(lvx, c1, -c1)), Zx);
            }
        }

        if (jt < 7) st_tile(bufW, pa, r0, c16);
        __syncthreads();
    }

    // combine lane-halves; coalesced SoA partial store
    wsum += __shfl_xor(wsum, 32, 64);
    ones += __shfl_xor(ones, 32, 64);
    Az += __shfl_xor(Az, 32, 64);
    Ax += __shfl_xor(Ax, 32, 64);
    Zz += __shfl_xor(Zz, 32, 64);
    Zx += __shfl_xor(Zx, 32, 64);
    if (half == 0) {
        float* pb = P + ((size_t)bj * 6) * 4096 + i;
        pb[0] = wsum;
        pb[4096] = ones;
        pb[2 * 4096] = Az;
        pb[3 * 4096] = Ax;
        pb[4 * 4096] = Zz;
        pb[5 * 4096] = Zx;
    }

    // ---- tail: per-group ticket; last arrival of group g reduces m=g ----
    __threadfence();
    __syncthreads();
    int g = bi >> 1;   // 16 groups x 64 blocks (2 bi x 32 bj)
    if (tid == 0) sFlag = atomicAdd(&ctrl[2 + g], 1u);
    __syncthreads();
    if (sFlag == 63u) {
        __threadfence();   // acquire group's P partials
        int row = g * 256 + tid;
        float tw = 0.f, to = 0.f, tAz = 0.f, tAx = 0.f, tZz = 0.f, tZx = 0.f;
#pragma unroll
        for (int c = 0; c < 32; ++c) {
            const float* pb = P + ((size_t)c * 6) * 4096 + row;
            tw += pb[0];
            to += pb[4096];
            tAz += pb[2 * 4096];
            tAx += pb[3 * 4096];
            tZz += pb[4 * 4096];
            tZx += pb[5 * 4096];
        }
        float dw = tw > 0.f ? tw : 1.0f;
        float lz = tZz > 0.f ? logf(tZz) : 0.f;
        float lx = tZx > 0.f ? logf(tZx) : 0.f;
        float mlz = (TEMP_INV * tAz - tw * (TEMP_INV + lz)) / dw;
        float mlx = (TEMP_INV * tAx - tw * (TEMP_INV + lx)) / dw;
        float si = to > 0.f ? tw : 0.f;
        float ci = (mlz + mlx) * si;
#pragma unroll
        for (int d = 1; d < 64; d <<= 1) {
            ci += __shfl_xor(ci, d, 64);
            si += __shfl_xor(si, d, 64);
        }
        if ((tid & 63) == 0) { sT[tid >> 6] = ci; sT[8 + (tid >> 6)] = si; }
        __syncthreads();
        if (tid == 0) {
            float cs = sT[0] + sT[1] + sT[2] + sT[3];
            float ss = sT[8] + sT[9] + sT[10] + sT[11];
            float ratio = ss > 0.f ? cs / ss : 0.f;
            float* accum = (float*)&ctrl[19];
            atomicAdd(accum, ratio);
            __threadfence();
            u32 old2 = atomicAdd(&ctrl[18], 1u);
            if (old2 == 15u) {
                float total = atomicAdd(accum, 0.0f);  // all 16 group adds complete
                __hip_bfloat16 hb = __float2bfloat16(-total / 32.0f);
                u32 bits = (u32)__bfloat16_as_ushort(hb);
                out[0] = (bits << 16) | bits;  // bf16/f32 dual-interpretation hedge (passed r3-r10)
            }
        }
    }
}

extern "C" void kernel_launch(void* const* d_in, const int* in_sizes, int n_in,
                              void* d_out, int out_size, void* d_ws, size_t ws_size,
                              hipStream_t stream) {
    const float* z   = (const float*)d_in[0];
    const float* spr = (const float*)d_in[1];
    const float* f   = (const float*)d_in[2];
    const float* pag = (const float*)d_in[3];
    const float* psp = (const float*)d_in[4];
    const float* zmx = (const float*)d_in[5];
    const float* mnb = (const float*)d_in[6];

    // ws: P[32][6][4096] f32 (3 MB) | Rf[4096] | Rs[4096] | ctrl[32]
    float* P  = (float*)d_ws;
    float* Rf = P + (size_t)32 * 6 * 4096;
    float* Rs = Rf + 4096;
    u32* ctrl = (u32*)(Rs + 4096);

    hipMemsetAsync(ctrl, 0, 128, stream);
    k_fused<<<dim3(32, 32), 256, 0, stream>>>(z, spr, f, zmx, pag, psp, mnb,
                                              P, Rf, Rs, ctrl, (u32*)d_out);
}